// Round 7
// baseline (457.036 us; speedup 1.0000x reference)
//
#include <hip/hip_runtime.h>
#include <hip/hip_bf16.h>
#include <stdint.h>

// ---------- types / helpers ----------
typedef float  f32x4  __attribute__((ext_vector_type(4)));
typedef float  f32x2  __attribute__((ext_vector_type(2)));
typedef short  bf16x8 __attribute__((ext_vector_type(8)));
typedef short  bf16x4 __attribute__((ext_vector_type(4)));

#define MFMA16(A,B,C) __builtin_amdgcn_mfma_f32_16x16x32_bf16(A,B,C,0,0,0)

__device__ __forceinline__ short f2bf(float x){
    union { float f; uint32_t u; } v; v.f = x;
    uint32_t r = v.u + 0x7fffu + ((v.u >> 16) & 1u);   // RNE (software)
    return (short)(r >> 16);
}
__device__ __forceinline__ float bf2f(short x){
    union { uint32_t u; float f; } v; v.u = ((uint32_t)(uint16_t)x) << 16;
    return v.f;
}
// HW packed conversion: v_cvt_pk_bf16_f32 via hip header (compiler-lowered)
__device__ __forceinline__ uint32_t cvt2(float lo, float hi){
    __hip_bfloat162 t = __float22bfloat162_rn(float2{lo, hi});
    union { __hip_bfloat162 b; uint32_t u; } c; c.b = t; return c.u;
}
__device__ __forceinline__ bf16x8 pack8(f32x4 a, f32x4 b){
    union { uint32_t u[4]; bf16x8 s; } c;
    c.u[0] = cvt2(a[0], a[1]); c.u[1] = cvt2(a[2], a[3]);
    c.u[2] = cvt2(b[0], b[1]); c.u[3] = cvt2(b[2], b[3]);
    return c.s;
}

// ---------- K0a: transpose Wq/Wk/Wv (fp32 [k][o]) -> WT bf16 [w][o][k] ----------
__global__ void k_prep_wt(const float* __restrict__ Wq, const float* __restrict__ Wk,
                          const float* __restrict__ Wv, short* __restrict__ WT){
    int blk = blockIdx.x;            // 192 = 3 * 64 tiles
    int w  = blk >> 6;
    int t  = blk & 63;
    int k0 = (t >> 3) << 6;
    int o0 = (t & 7) << 6;
    const float* W = (w == 0) ? Wq : ((w == 1) ? Wk : Wv);
    __shared__ float tile[64][65];
    int tx = threadIdx.x & 63, ty = threadIdx.x >> 6;    // ty 0..3
    #pragma unroll
    for (int i = 0; i < 64; i += 4)
        tile[ty + i][tx] = W[(size_t)(k0 + ty + i) * 512 + o0 + tx];
    __syncthreads();
    short* out = WT + (size_t)w * 512 * 512;
    #pragma unroll
    for (int i = 0; i < 64; i += 4)
        out[(size_t)(o0 + ty + i) * 512 + k0 + tx] = f2bf(tile[tx][ty + i]);
}

// ---------- K0b: WcatT bf16 [16ch][32c] (ch<8: We, ch>=8: Wg), bcat f32[16] ----------
__global__ void k_prep_wcat(const float* __restrict__ We, const float* __restrict__ Wg,
                            const float* __restrict__ be, const float* __restrict__ bg,
                            short* __restrict__ WcatT, float* __restrict__ bcat){
    int t = threadIdx.x;             // 512 threads
    int ch = t >> 5, c = t & 31;
    float v = (ch < 8) ? We[c * 8 + ch] : Wg[c * 8 + (ch - 8)];
    WcatT[ch * 32 + c] = f2bf(v);
    if (t < 16) bcat[t] = (t < 8) ? be[t] : bg[t - 8];
}

// ---------- K0c: nodes fp32 -> bf16 ----------
__global__ void k_prep_nodes(const float* __restrict__ nodes, short* __restrict__ nb){
    size_t i = ((size_t)blockIdx.x * 256 + threadIdx.x) * 8;
    f32x4 a = *(const f32x4*)(nodes + i);
    f32x4 b = *(const f32x4*)(nodes + i + 4);
    *(bf16x8*)(nb + i) = pack8(a, b);
}

// ---------- K1: QKV projections (sector-dense staged stores) ----------
// q,k -> [b][h][l][64] bf16 ; v -> [b][h][64][m] bf16
__global__ void k_qkv(const short* __restrict__ nodesbf, const short* __restrict__ WT,
                      const float* __restrict__ bq, const float* __restrict__ bk,
                      const float* __restrict__ bv,
                      short* __restrict__ qb, short* __restrict__ kb, short* __restrict__ vTb){
    int bx = blockIdx.x;             // 1536
    int lt = bx & 255;
    int ob = bx >> 8;                // 0..5
    int wave = threadIdx.x >> 6, lane = threadIdx.x & 63;
    int lr = lane & 15, lg = lane >> 4;
    int row0 = lt << 4;
    int og = ob * 256 + wave * 64;
    int w  = og >> 9;                // 0=q,1=k,2=v
    int oo = og & 511;
    int dhalf = ob & 1;              // which 32-wide d half this block owns

    const short* Wp = WT + (size_t)w * 512 * 512;
    f32x4 acc[4] = {};
    const short* arow = nodesbf + (size_t)(row0 + lr) * 512 + lg * 8;
    #pragma unroll
    for (int kk = 0; kk < 16; ++kk){
        bf16x8 af = *(const bf16x8*)(arow + kk * 32);
        #pragma unroll
        for (int s = 0; s < 4; ++s){
            const short* bp = Wp + (size_t)(oo + s * 16 + lr) * 512 + kk * 32 + lg * 8;
            bf16x8 bfv = *(const bf16x8*)bp;
            acc[s] = MFMA16(af, bfv, acc[s]);
        }
    }
    const float* bias = (w == 0) ? bq : ((w == 1) ? bk : bv);
    int b  = row0 >> 10;
    int lbase = row0 & 1023;

    __shared__ short St[4096];       // q/k: [l16][h8][dd32]  v: [h8][dd32][m16]
    #pragma unroll
    for (int s = 0; s < 4; ++s){
        int o = oo + s * 16 + lr;
        float bsv = bias[o];
        int h = o & 7, dd = (o >> 3) & 31;
        #pragma unroll
        for (int r = 0; r < 4; ++r){
            short sv = f2bf(acc[s][r] + bsv);
            int l = lg * 4 + r;
            if (w < 2) St[(l << 8) + (h << 5) + dd] = sv;
            else       St[(h << 9) + (dd << 4) + l] = sv;
        }
    }
    __syncthreads();
    int t = threadIdx.x;
    bf16x8 v0 = *(const bf16x8*)&St[t * 16];
    bf16x8 v1 = *(const bf16x8*)&St[t * 16 + 8];
    if (w < 2){
        short* dst = (w == 0) ? qb : kb;
        int l = t >> 4, h = (t >> 1) & 7, dd0 = (t & 1) << 4;
        size_t a = ((size_t)(b * 8 + h) * 1024 + lbase + l) * 64 + dhalf * 32 + dd0;
        *(bf16x8*)(dst + a)     = v0;
        *(bf16x8*)(dst + a + 8) = v1;
    } else {
        int h = t >> 5, dd = t & 31;
        size_t a = ((size_t)(b * 8 + h) * 64 + dhalf * 32 + dd) * 1024 + lbase;
        *(bf16x8*)(vTb + a)     = v0;
        *(bf16x8*)(vTb + a + 8) = v1;
    }
}

// ---------- K2a: scores/H/exp/sigmoid — S^T orientation, single-pass epilogue ----------
// *** PROBE ROUND: launched with grid 8192 = 2 x 4096; blocks >= 4096 redo the
// *** same tile (identical values to identical addresses — idempotent). This
// *** doubles the dispatch duration so it (a) is measurable via total-time
// *** delta and (b) surfaces in the top-5 counter table if it is the hog.
__global__ __launch_bounds__(256, 3) void k_hsg(
        const float* __restrict__ edges, const short* __restrict__ qb,
        const short* __restrict__ kb, const short* __restrict__ WcatT,
        const float* __restrict__ bcat,
        float* __restrict__ Hout, short* __restrict__ Pb,
        float* __restrict__ psum){
    int bx = blockIdx.x & 4095;                // PROBE: fold the second copy
    int j  = bx & 7;  int b = j >> 1;          // XCD j sees a single batch b
    int rest = bx >> 3;
    int mt = rest & 15;
    int lt = (rest >> 4) | ((j & 1) << 5);
    int w = threadIdx.x >> 6, lane = threadIdx.x & 63;
    int lr = lane & 15, lg = lane >> 4;
    int l0 = lt << 4;
    int mg = (mt << 6) + (w << 4);
    const size_t bl0 = (size_t)(b * 1024 + l0);

    __shared__ short eg[4][4096];    // per-wave [l16][m16][ch16] bf16, swizzled
    char* egw = (char*)&eg[w][0];
    const int swz = (lr & 7) << 4;   // read-side XOR (row = l = lr)

    // ---- prefetch edge chunk 0 (hides HBM latency under qk phase) ----
    f32x4 ebA[4][2], ebB[4][2];
    #pragma unroll
    for (int i = 0; i < 4; ++i){
        const float* ep = edges + ((bl0 + i) * 1024 + mg + lr) * 32 + lg * 8;
        ebA[i][0] = *(const f32x4*)ep;
        ebA[i][1] = *(const f32x4*)(ep + 4);
    }

    // ---- qk (swapped): S^T[h]: col=l=lr, row=m-local=4lg+rr ----
    f32x4 S[8] = {};
    #pragma unroll
    for (int h = 0; h < 8; ++h){
        #pragma unroll
        for (int half = 0; half < 2; ++half){
            bf16x8 kf = *(const bf16x8*)(kb + ((size_t)(b * 8 + h) * 1024 + mg + lr) * 64 + half * 32 + lg * 8);
            bf16x8 qf = *(const bf16x8*)(qb + ((size_t)(b * 8 + h) * 1024 + l0 + lr) * 64 + half * 32 + lg * 8);
            S[h] = MFMA16(kf, qf, S[h]);   // A=K (row=m), B=Q (col=l)
        }
    }

    // ---- e/g: one MFMA per l, D[ch][m]: lane (m=lr, ch=4lg+rr) ----
    bf16x8 wf = *(const bf16x8*)(WcatT + lr * 32 + lg * 8);   // A: row=ch, k=c
    f32x4  bc = *(const f32x4*)(bcat + lg * 4);               // ch = 4lg+rr
    f32x4 zero = {0.f, 0.f, 0.f, 0.f};
    #pragma unroll
    for (int c = 0; c < 4; ++c){
        if (c < 3){                   // prefetch next 4-l chunk
            #pragma unroll
            for (int i = 0; i < 4; ++i){
                const float* ep = edges + ((bl0 + (c + 1) * 4 + i) * 1024 + mg + lr) * 32 + lg * 8;
                if (c & 1){ ebA[i][0] = *(const f32x4*)ep; ebA[i][1] = *(const f32x4*)(ep + 4); }
                else      { ebB[i][0] = *(const f32x4*)ep; ebB[i][1] = *(const f32x4*)(ep + 4); }
            }
        }
        #pragma unroll
        for (int i = 0; i < 4; ++i){
            int l = c * 4 + i;
            f32x4 e0 = (c & 1) ? ebB[i][0] : ebA[i][0];
            f32x4 e1 = (c & 1) ? ebB[i][1] : ebA[i][1];
            f32x4 d = MFMA16(wf, pack8(e0, e1), zero);
            union { uint32_t u[2]; bf16x4 v; } dv;
            dv.u[0] = cvt2(d[0] + bc[0], d[1] + bc[1]);
            dv.u[1] = cvt2(d[2] + bc[2], d[3] + bc[3]);
            int bw = (l * 512 + lr * 32 + lg * 8) ^ ((l & 7) << 4);
            *(bf16x4*)(egw + bw) = dv.v;   // [l][m=lr][ch=4lg..+3]
        }
    }

    // ---- single-pass epilogue: lane owns (l=lr, m=mg+4lg+rr, all h) ----
    float exu[4][8], pgv[4][8];
    #pragma unroll
    for (int rr = 0; rr < 4; ++rr){
        int base = lr * 512 + (4 * lg + rr) * 32;
        bf16x8 e8 = *(const bf16x8*)(egw + ((base)      ^ swz));
        bf16x8 g8 = *(const bf16x8*)(egw + ((base + 16) ^ swz));
        float Hv[8];
        #pragma unroll
        for (int h = 0; h < 8; ++h){
            float s = S[h][rr] * 0.125f;
            s = fminf(fmaxf(s, -5.f), 5.f);
            float hv = s + bf2f(e8[h]);
            Hv[h] = hv;
            float ex = __expf(hv);
            exu[rr][h] = ex;
            float sg = __builtin_amdgcn_rcpf(1.f + __expf(-bf2f(g8[h])));
            pgv[rr][h] = ex * sg;
        }
        // H: 8 consecutive floats (all heads) per lane — direct dwordx4 pair
        float* hp = Hout + (bl0 + lr) * 8192 + (size_t)(mg + 4 * lg + rr) * 8;
        f32x4 h0 = {Hv[0], Hv[1], Hv[2], Hv[3]};
        f32x4 h1 = {Hv[4], Hv[5], Hv[6], Hv[7]};
        *(f32x4*)hp       = h0;
        *(f32x4*)(hp + 4) = h1;
    }

    // ---- P (tile-major, direct bf16x4 per h) + psum (2 shfl per h) ----
    size_t ptile = ((size_t)(b * 8) * 64 + lt) * 64 + (mt * 4 + w);
    size_t psbase = (((size_t)(b * 64 + lt) * 16 + mt) * 4 + w) * 128;
    #pragma unroll
    for (int h = 0; h < 8; ++h){
        union { uint32_t u[2]; bf16x4 v; } pv;
        pv.u[0] = cvt2(pgv[0][h], pgv[1][h]);
        pv.u[1] = cvt2(pgv[2][h], pgv[3][h]);
        *(bf16x4*)(Pb + (ptile + (size_t)h * 4096) * 256 + lr * 16 + lg * 4) = pv.v;
        float t = exu[0][h] + exu[1][h] + exu[2][h] + exu[3][h];
        t += __shfl_xor(t, 16);
        t += __shfl_xor(t, 32);
        if (lg == 0) psum[psbase + h * 16 + lr] = t;
    }
}

// ---------- K2b: O = (P @ v) / rowsum — streaming MFMA over tile-major P ----------
// grid 256 = b x lt (XCD-swizzled); block 512 = 8 waves, wave = head
__global__ void k_pv(const short* __restrict__ Pb, const float* __restrict__ psum,
                     const short* __restrict__ vTb, float* __restrict__ attn){
    int bx = blockIdx.x;
    int j  = bx & 7;  int b = j >> 1;
    int lt = ((j & 1) << 5) | (bx >> 3);
    int h    = threadIdx.x >> 6;
    int lane = threadIdx.x & 63;
    int lr = lane & 15, lg = lane >> 4;
    int l0 = lt << 4;

    const short* Pbase = Pb  + (((size_t)(b * 8 + h) * 64 + lt) * 64) * 256;
    const short* vbase = vTb + (size_t)(b * 8 + h) * 65536;

    f32x4 O[4] = {};
    for (int ks = 0; ks < 32; ++ks){
        // B-frag: col=l=lr, k = m-local; tile T = ks*2 + (lg>>1)
        bf16x8 pf = *(const bf16x8*)(Pbase + (ks * 2 + (lg >> 1)) * 256 + lr * 16 + (lg & 1) * 8);
        #pragma unroll
        for (int dt = 0; dt < 4; ++dt){
            bf16x8 vf = *(const bf16x8*)(vbase + (size_t)(dt * 16 + lr) * 1024 + ks * 32 + lg * 8);
            O[dt] = MFMA16(vf, pf, O[dt]);
        }
    }

    // denominator: sum 64 partials per (h, l=lr)
    const float* pp = psum + ((size_t)(b * 64 + lt) * 16) * 512;
    float ds = 0.f;
    #pragma unroll
    for (int c = 0; c < 16; ++c)
        ds += pp[(c * 4 + lg) * 128 + h * 16 + lr];
    ds += __shfl_xor(ds, 16);
    ds += __shfl_xor(ds, 32);
    float inv = __builtin_amdgcn_rcpf(ds);

    // stage normalized O, block-coalesced dense write
    __shared__ float Os[16][516];
    #pragma unroll
    for (int dt = 0; dt < 4; ++dt){
        #pragma unroll
        for (int r = 0; r < 4; ++r)
            Os[lr][(dt * 16 + lg * 4 + r) * 8 + h] = O[dt][r] * inv;   // d = dt*16+4lg+r, l = lr
    }
    __syncthreads();
    int row = threadIdx.x >> 5;          // 0..15
    int cb  = (threadIdx.x & 31) * 16;   // 0..496
    float* dst = attn + ((size_t)(b * 1024 + l0 + row)) * 512 + cb;
    #pragma unroll
    for (int jj = 0; jj < 16; jj += 4)
        *(f32x4*)(dst + jj) = *(const f32x4*)&Os[row][cb + jj];
}

// ---------- workspace layout ----------
#define OFF_WT    ((size_t)0x0000000)   // 1.5 MB
#define OFF_WCAT  ((size_t)0x0180000)   // 1 KB
#define OFF_BCAT  ((size_t)0x0180400)   // 64 B
#define OFF_NB    ((size_t)0x0200000)   // 4 MB (nodes bf16)
#define OFF_Q     ((size_t)0x0600000)   // 4 MB
#define OFF_K     ((size_t)0x0A00000)   // 4 MB
#define OFF_VT    ((size_t)0x0E00000)   // 4 MB
#define OFF_P     ((size_t)0x1200000)   // 64 MB (P bf16 tile-major)
#define OFF_PS    ((size_t)0x5200000)   // 8.4 MB (psum f32) -> total ~95 MB

extern "C" void kernel_launch(void* const* d_in, const int* in_sizes, int n_in,
                              void* d_out, int out_size, void* d_ws, size_t ws_size,
                              hipStream_t stream) {
    const float* nodes = (const float*)d_in[0];
    const float* edges = (const float*)d_in[1];
    const float* Wq = (const float*)d_in[2];
    const float* bq = (const float*)d_in[3];
    const float* Wk = (const float*)d_in[4];
    const float* bk = (const float*)d_in[5];
    const float* Wv = (const float*)d_in[6];
    const float* bv = (const float*)d_in[7];
    const float* Wg = (const float*)d_in[8];
    const float* bg = (const float*)d_in[9];
    const float* We = (const float*)d_in[10];
    const float* be = (const float*)d_in[11];

    float* out_attn = (float*)d_out;
    float* out_H    = out_attn + (size_t)4 * 1024 * 512;

    char* ws = (char*)d_ws;
    short* WT    = (short*)(ws + OFF_WT);
    short* WcatT = (short*)(ws + OFF_WCAT);
    float* bcat  = (float*)(ws + OFF_BCAT);
    short* nb    = (short*)(ws + OFF_NB);
    short* qb    = (short*)(ws + OFF_Q);
    short* kb    = (short*)(ws + OFF_K);
    short* vTb   = (short*)(ws + OFF_VT);
    short* Pb    = (short*)(ws + OFF_P);
    float* psum  = (float*)(ws + OFF_PS);

    k_prep_wt   <<<192, 256, 0, stream>>>(Wq, Wk, Wv, WT);
    k_prep_wcat <<<1, 512, 0, stream>>>(We, Wg, be, bg, WcatT, bcat);
    k_prep_nodes<<<1024, 256, 0, stream>>>(nodes, nb);
    k_qkv       <<<1536, 256, 0, stream>>>(nb, WT, bq, bk, bv, qb, kb, vTb);
    // PROBE: 2x grid — duplicate idempotent work to measure t_hsg via total
    // delta and surface k_hsg in the top-5 counter table if it dominates.
    k_hsg       <<<8192, 256, 0, stream>>>(edges, qb, kb, WcatT, bcat, out_H, Pb, psum);
    k_pv        <<<256, 512, 0, stream>>>(Pb, psum, vTb, out_attn);
}

// Round 8
// 291.885 us; speedup vs baseline: 1.5658x; 1.5658x over previous
//
#include <hip/hip_runtime.h>
#include <hip/hip_bf16.h>
#include <stdint.h>

// ---------- types / helpers ----------
typedef float  f32x4  __attribute__((ext_vector_type(4)));
typedef float  f32x2  __attribute__((ext_vector_type(2)));
typedef short  bf16x8 __attribute__((ext_vector_type(8)));
typedef short  bf16x4 __attribute__((ext_vector_type(4)));

#define MFMA16(A,B,C) __builtin_amdgcn_mfma_f32_16x16x32_bf16(A,B,C,0,0,0)

__device__ __forceinline__ short f2bf(float x){
    union { float f; uint32_t u; } v; v.f = x;
    uint32_t r = v.u + 0x7fffu + ((v.u >> 16) & 1u);   // RNE (software)
    return (short)(r >> 16);
}
__device__ __forceinline__ float bf2f(short x){
    union { uint32_t u; float f; } v; v.u = ((uint32_t)(uint16_t)x) << 16;
    return v.f;
}
__device__ __forceinline__ uint32_t cvt2(float lo, float hi){
    __hip_bfloat162 t = __float22bfloat162_rn(float2{lo, hi});
    union { __hip_bfloat162 b; uint32_t u; } c; c.b = t; return c.u;
}
__device__ __forceinline__ bf16x8 pack8(f32x4 a, f32x4 b){
    union { uint32_t u[4]; bf16x8 s; } c;
    c.u[0] = cvt2(a[0], a[1]); c.u[1] = cvt2(a[2], a[3]);
    c.u[2] = cvt2(b[0], b[1]); c.u[3] = cvt2(b[2], b[3]);
    return c.s;
}

// ---------- K0: fused prep (Wq/Wk/Wv transpose | Wcat | nodes->bf16) ----------
__global__ void k_prep(const float* __restrict__ Wq, const float* __restrict__ Wk,
                       const float* __restrict__ Wv, const float* __restrict__ We,
                       const float* __restrict__ Wg, const float* __restrict__ be,
                       const float* __restrict__ bg, const float* __restrict__ nodes,
                       short* __restrict__ WT, short* __restrict__ WcatT,
                       float* __restrict__ bcat, short* __restrict__ nb){
    int blk = blockIdx.x;
    if (blk < 192){                       // W transpose: 3 x 64 tiles
        int w  = blk >> 6;
        int t  = blk & 63;
        int k0 = (t >> 3) << 6;
        int o0 = (t & 7) << 6;
        const float* W = (w == 0) ? Wq : ((w == 1) ? Wk : Wv);
        __shared__ float tile[64][65];
        int tx = threadIdx.x & 63, ty = threadIdx.x >> 6;
        #pragma unroll
        for (int i = 0; i < 64; i += 4)
            tile[ty + i][tx] = W[(size_t)(k0 + ty + i) * 512 + o0 + tx];
        __syncthreads();
        short* out = WT + (size_t)w * 512 * 512;
        #pragma unroll
        for (int i = 0; i < 64; i += 4)
            out[(size_t)(o0 + ty + i) * 512 + k0 + tx] = f2bf(tile[tx][ty + i]);
    } else if (blk == 192){               // Wcat + bcat
        #pragma unroll
        for (int i = 0; i < 2; ++i){
            int t = i * 256 + threadIdx.x;
            int ch = t >> 5, c = t & 31;
            float v = (ch < 8) ? We[c * 8 + ch] : Wg[c * 8 + (ch - 8)];
            WcatT[ch * 32 + c] = f2bf(v);
        }
        if (threadIdx.x < 16) bcat[threadIdx.x] = (threadIdx.x < 8) ? be[threadIdx.x] : bg[threadIdx.x - 8];
    } else {                              // nodes fp32 -> bf16 (1024 blocks)
        size_t i = ((size_t)(blk - 193) * 256 + threadIdx.x) * 8;
        f32x4 a = *(const f32x4*)(nodes + i);
        f32x4 b = *(const f32x4*)(nodes + i + 4);
        *(bf16x8*)(nb + i) = pack8(a, b);
    }
}

// ---------- K1: QKV projections (sector-dense staged stores) ----------
// q,k -> [b][h][l][64] bf16 ; v -> [b][h][64][m] bf16
__global__ void k_qkv(const short* __restrict__ nodesbf, const short* __restrict__ WT,
                      const float* __restrict__ bq, const float* __restrict__ bk,
                      const float* __restrict__ bv,
                      short* __restrict__ qb, short* __restrict__ kb, short* __restrict__ vTb){
    int bx = blockIdx.x;             // 1536
    int lt = bx & 255;
    int ob = bx >> 8;                // 0..5
    int wave = threadIdx.x >> 6, lane = threadIdx.x & 63;
    int lr = lane & 15, lg = lane >> 4;
    int row0 = lt << 4;
    int og = ob * 256 + wave * 64;
    int w  = og >> 9;                // 0=q,1=k,2=v
    int oo = og & 511;
    int dhalf = ob & 1;

    const short* Wp = WT + (size_t)w * 512 * 512;
    f32x4 acc[4] = {};
    const short* arow = nodesbf + (size_t)(row0 + lr) * 512 + lg * 8;
    #pragma unroll
    for (int kk = 0; kk < 16; ++kk){
        bf16x8 af = *(const bf16x8*)(arow + kk * 32);
        #pragma unroll
        for (int s = 0; s < 4; ++s){
            const short* bp = Wp + (size_t)(oo + s * 16 + lr) * 512 + kk * 32 + lg * 8;
            bf16x8 bfv = *(const bf16x8*)bp;
            acc[s] = MFMA16(af, bfv, acc[s]);
        }
    }
    const float* bias = (w == 0) ? bq : ((w == 1) ? bk : bv);
    int b  = row0 >> 10;
    int lbase = row0 & 1023;

    __shared__ short St[4096];       // q/k: [l16][h8][dd32]  v: [h8][dd32][m16]
    #pragma unroll
    for (int s = 0; s < 4; ++s){
        int o = oo + s * 16 + lr;
        float bsv = bias[o];
        int h = o & 7, dd = (o >> 3) & 31;
        #pragma unroll
        for (int r = 0; r < 4; ++r){
            short sv = f2bf(acc[s][r] + bsv);
            int l = lg * 4 + r;
            if (w < 2) St[(l << 8) + (h << 5) + dd] = sv;
            else       St[(h << 9) + (dd << 4) + l] = sv;
        }
    }
    __syncthreads();
    int t = threadIdx.x;
    bf16x8 v0 = *(const bf16x8*)&St[t * 16];
    bf16x8 v1 = *(const bf16x8*)&St[t * 16 + 8];
    if (w < 2){
        short* dst = (w == 0) ? qb : kb;
        int l = t >> 4, h = (t >> 1) & 7, dd0 = (t & 1) << 4;
        size_t a = ((size_t)(b * 8 + h) * 1024 + lbase + l) * 64 + dhalf * 32 + dd0;
        *(bf16x8*)(dst + a)     = v0;
        *(bf16x8*)(dst + a + 8) = v1;
    } else {
        int h = t >> 5, dd = t & 31;
        size_t a = ((size_t)(b * 8 + h) * 64 + dhalf * 32 + dd) * 1024 + lbase;
        *(bf16x8*)(vTb + a)     = v0;
        *(bf16x8*)(vTb + a + 8) = v1;
    }
}

// ---------- K2a: scores/H/exp/sigmoid — VGPR-lean streaming epilogue ----------
// grid 4096 = b(4) x lt(64) x mt(16), XCD-swizzled; block 256 = 4 waves, wave = m-16.
// S^T = mfma(K,Q): lane owns (l=lr, m=mg+4lg+rr). Epilogue streams per rr-pair:
// dsum[8] accumulators + pu[2][8] packed P replace the old 64-float arrays
// (occupancy was VGPR-capped at ~14 waves/CU per round-7 probe).
__global__ __launch_bounds__(256, 4) void k_hsg(
        const float* __restrict__ edges, const short* __restrict__ qb,
        const short* __restrict__ kb, const short* __restrict__ WcatT,
        const float* __restrict__ bcat,
        float* __restrict__ Hout, short* __restrict__ Pb,
        float* __restrict__ psum){
    int bx = blockIdx.x;
    int j  = bx & 7;  int b = j >> 1;          // XCD j sees a single batch b
    int rest = bx >> 3;
    int mt = rest & 15;
    int lt = (rest >> 4) | ((j & 1) << 5);
    int w = threadIdx.x >> 6, lane = threadIdx.x & 63;
    int lr = lane & 15, lg = lane >> 4;
    int l0 = lt << 4;
    int mg = (mt << 6) + (w << 4);
    const size_t bl0 = (size_t)(b * 1024 + l0);

    __shared__ short eg[4][4096];    // per-wave [l16][m16][ch16] bf16, swizzled
    char* egw = (char*)&eg[w][0];
    const int swz = (lr & 7) << 4;   // read-side XOR (row = l = lr)

    // ---- prefetch edge chunk 0 ----
    f32x4 ebA[4][2], ebB[4][2];
    #pragma unroll
    for (int i = 0; i < 4; ++i){
        const float* ep = edges + ((bl0 + i) * 1024 + mg + lr) * 32 + lg * 8;
        ebA[i][0] = *(const f32x4*)ep;
        ebA[i][1] = *(const f32x4*)(ep + 4);
    }

    // ---- qk (swapped): S^T[h]: col=l=lr, row=m-local=4lg+rr ----
    f32x4 S[8] = {};
    #pragma unroll
    for (int h = 0; h < 8; ++h){
        #pragma unroll
        for (int half = 0; half < 2; ++half){
            bf16x8 kf = *(const bf16x8*)(kb + ((size_t)(b * 8 + h) * 1024 + mg + lr) * 64 + half * 32 + lg * 8);
            bf16x8 qf = *(const bf16x8*)(qb + ((size_t)(b * 8 + h) * 1024 + l0 + lr) * 64 + half * 32 + lg * 8);
            S[h] = MFMA16(kf, qf, S[h]);   // A=K (row=m), B=Q (col=l)
        }
    }

    // ---- e/g: one MFMA per l, D[ch][m]: lane (m=lr, ch=4lg+rr) ----
    bf16x8 wf = *(const bf16x8*)(WcatT + lr * 32 + lg * 8);
    f32x4  bc = *(const f32x4*)(bcat + lg * 4);
    f32x4 zero = {0.f, 0.f, 0.f, 0.f};
    #pragma unroll
    for (int c = 0; c < 4; ++c){
        if (c < 3){                   // prefetch next 4-l chunk
            #pragma unroll
            for (int i = 0; i < 4; ++i){
                const float* ep = edges + ((bl0 + (c + 1) * 4 + i) * 1024 + mg + lr) * 32 + lg * 8;
                if (c & 1){ ebA[i][0] = *(const f32x4*)ep; ebA[i][1] = *(const f32x4*)(ep + 4); }
                else      { ebB[i][0] = *(const f32x4*)ep; ebB[i][1] = *(const f32x4*)(ep + 4); }
            }
        }
        #pragma unroll
        for (int i = 0; i < 4; ++i){
            int l = c * 4 + i;
            f32x4 e0 = (c & 1) ? ebB[i][0] : ebA[i][0];
            f32x4 e1 = (c & 1) ? ebB[i][1] : ebA[i][1];
            f32x4 d = MFMA16(wf, pack8(e0, e1), zero);
            union { uint32_t u[2]; bf16x4 v; } dv;
            dv.u[0] = cvt2(d[0] + bc[0], d[1] + bc[1]);
            dv.u[1] = cvt2(d[2] + bc[2], d[3] + bc[3]);
            int bw = (l * 512 + lr * 32 + lg * 8) ^ ((l & 7) << 4);
            *(bf16x4*)(egw + bw) = dv.v;
        }
    }

    // ---- streaming epilogue: lane owns (l=lr, m=mg+4lg+rr, all h) ----
    float dsum[8] = {0.f,0.f,0.f,0.f,0.f,0.f,0.f,0.f};
    uint32_t pu[2][8];
    #pragma unroll
    for (int pr = 0; pr < 2; ++pr){
        float pgE[8];
        #pragma unroll
        for (int rr2 = 0; rr2 < 2; ++rr2){
            int rr = pr * 2 + rr2;
            int base = lr * 512 + (4 * lg + rr) * 32;
            bf16x8 e8 = *(const bf16x8*)(egw + ((base)      ^ swz));
            bf16x8 g8 = *(const bf16x8*)(egw + ((base + 16) ^ swz));
            float Hv[8];
            #pragma unroll
            for (int h = 0; h < 8; ++h){
                float s = S[h][rr] * 0.125f;
                s = fminf(fmaxf(s, -5.f), 5.f);
                float hv = s + bf2f(e8[h]);
                Hv[h] = hv;
                float ex = __expf(hv);
                dsum[h] += ex;
                float sg = __builtin_amdgcn_rcpf(1.f + __expf(-bf2f(g8[h])));
                float pg = ex * sg;
                if (rr2 == 0) pgE[h] = pg;
                else          pu[pr][h] = cvt2(pgE[h], pg);
            }
            float* hp = Hout + (bl0 + lr) * 8192 + (size_t)(mg + 4 * lg + rr) * 8;
            f32x4 h0 = {Hv[0], Hv[1], Hv[2], Hv[3]};
            f32x4 h1 = {Hv[4], Hv[5], Hv[6], Hv[7]};
            *(f32x4*)hp       = h0;
            *(f32x4*)(hp + 4) = h1;
        }
    }

    // ---- P (tile-major, bf16x4 per h) + psum ----
    size_t ptile = ((size_t)(b * 8) * 64 + lt) * 64 + (mt * 4 + w);
    size_t psbase = (((size_t)(b * 64 + lt) * 16 + mt) * 4 + w) * 128;
    #pragma unroll
    for (int h = 0; h < 8; ++h){
        union { uint32_t u[2]; bf16x4 v; } pv;
        pv.u[0] = pu[0][h]; pv.u[1] = pu[1][h];
        *(bf16x4*)(Pb + (ptile + (size_t)h * 4096) * 256 + lr * 16 + lg * 4) = pv.v;
        float t = dsum[h];
        t += __shfl_xor(t, 16);
        t += __shfl_xor(t, 32);
        if (lg == 0) psum[psbase + h * 16 + lr] = t;
    }
}

// ---------- K2b: O = (P @ v) / rowsum — 4 heads x 2 m-halves per block ----------
// grid 512 = b(4) x lt(64) x hg(2), XCD-swizzled; block 512 = 8 waves.
// wave w: head = hg*4 + (w>>1), m-half = w&1. Partial O combined via LDS.
__global__ void k_pv(const short* __restrict__ Pb, const float* __restrict__ psum,
                     const short* __restrict__ vTb, float* __restrict__ attn){
    int bx = blockIdx.x;
    int j  = bx & 7;  int b = j >> 1;
    int rest = bx >> 3;              // 0..63
    int hg = rest >> 5;              // 0..1
    int lt = ((j & 1) << 5) | (rest & 31);
    int w    = threadIdx.x >> 6;
    int lane = threadIdx.x & 63;
    int lr = lane & 15, lg = lane >> 4;
    int l0 = lt << 4;
    int head = hg * 4 + (w >> 1);
    int half = w & 1;

    const short* Pbase = Pb  + (((size_t)(b * 8 + head) * 64 + lt) * 64) * 256;
    const short* vbase = vTb + (size_t)(b * 8 + head) * 65536;

    f32x4 O[4] = {};
    for (int ks = half * 16; ks < half * 16 + 16; ++ks){
        bf16x8 pf = *(const bf16x8*)(Pbase + (ks * 2 + (lg >> 1)) * 256 + lr * 16 + (lg & 1) * 8);
        #pragma unroll
        for (int dt = 0; dt < 4; ++dt){
            bf16x8 vf = *(const bf16x8*)(vbase + (size_t)(dt * 16 + lr) * 1024 + ks * 32 + lg * 8);
            O[dt] = MFMA16(vf, pf, O[dt]);
        }
    }

    // denominator (full m), same for both halves
    const float* pp = psum + ((size_t)(b * 64 + lt) * 16) * 512;
    float ds = 0.f;
    #pragma unroll
    for (int c = 0; c < 16; ++c)
        ds += pp[(c * 4 + lg) * 128 + head * 16 + lr];
    ds += __shfl_xor(ds, 16);
    ds += __shfl_xor(ds, 32);
    float inv = __builtin_amdgcn_rcpf(ds);

    __shared__ float Opart[4][16][64];   // odd-half partials
    __shared__ float Os[16][260];        // col = d*4 + head-in-group
    if (half == 1){
        #pragma unroll
        for (int dt = 0; dt < 4; ++dt)
            #pragma unroll
            for (int r = 0; r < 4; ++r)
                Opart[w >> 1][lr][dt * 16 + lg * 4 + r] = O[dt][r];
    }
    __syncthreads();
    if (half == 0){
        #pragma unroll
        for (int dt = 0; dt < 4; ++dt)
            #pragma unroll
            for (int r = 0; r < 4; ++r){
                int d = dt * 16 + lg * 4 + r;
                float o = O[dt][r] + Opart[w >> 1][lr][d];
                Os[lr][d * 4 + (w >> 1)] = o * inv;
            }
    }
    __syncthreads();
    // write: 16 rows x 256 floats (4 heads interleaved at stride 8)
    int row = threadIdx.x >> 5;
    int c0  = (threadIdx.x & 31) * 8;    // Os col base (= d0*4, d0 = (t&31)*2)
    float* dst = attn + ((size_t)(b * 1024 + l0 + row)) * 512 + (threadIdx.x & 31) * 16 + hg * 4;
    *(f32x4*)dst       = *(const f32x4*)&Os[row][c0];
    *(f32x4*)(dst + 8) = *(const f32x4*)&Os[row][c0 + 4];
}

// ---------- workspace layout ----------
#define OFF_WT    ((size_t)0x0000000)   // 1.5 MB
#define OFF_WCAT  ((size_t)0x0180000)   // 1 KB
#define OFF_BCAT  ((size_t)0x0180400)   // 64 B
#define OFF_NB    ((size_t)0x0200000)   // 4 MB (nodes bf16)
#define OFF_Q     ((size_t)0x0600000)   // 4 MB
#define OFF_K     ((size_t)0x0A00000)   // 4 MB
#define OFF_VT    ((size_t)0x0E00000)   // 4 MB
#define OFF_P     ((size_t)0x1200000)   // 64 MB (P bf16 tile-major)
#define OFF_PS    ((size_t)0x5200000)   // 8.4 MB (psum f32) -> total ~95 MB

extern "C" void kernel_launch(void* const* d_in, const int* in_sizes, int n_in,
                              void* d_out, int out_size, void* d_ws, size_t ws_size,
                              hipStream_t stream) {
    const float* nodes = (const float*)d_in[0];
    const float* edges = (const float*)d_in[1];
    const float* Wq = (const float*)d_in[2];
    const float* bq = (const float*)d_in[3];
    const float* Wk = (const float*)d_in[4];
    const float* bk = (const float*)d_in[5];
    const float* Wv = (const float*)d_in[6];
    const float* bv = (const float*)d_in[7];
    const float* Wg = (const float*)d_in[8];
    const float* bg = (const float*)d_in[9];
    const float* We = (const float*)d_in[10];
    const float* be = (const float*)d_in[11];

    float* out_attn = (float*)d_out;
    float* out_H    = out_attn + (size_t)4 * 1024 * 512;

    char* ws = (char*)d_ws;
    short* WT    = (short*)(ws + OFF_WT);
    short* WcatT = (short*)(ws + OFF_WCAT);
    float* bcat  = (float*)(ws + OFF_BCAT);
    short* nb    = (short*)(ws + OFF_NB);
    short* qb    = (short*)(ws + OFF_Q);
    short* kb    = (short*)(ws + OFF_K);
    short* vTb   = (short*)(ws + OFF_VT);
    short* Pb    = (short*)(ws + OFF_P);
    float* psum  = (float*)(ws + OFF_PS);

    k_prep <<<1217, 256, 0, stream>>>(Wq, Wk, Wv, We, Wg, be, bg, nodes,
                                      WT, WcatT, bcat, nb);
    k_qkv  <<<1536, 256, 0, stream>>>(nb, WT, bq, bk, bv, qb, kb, vTb);
    k_hsg  <<<4096, 256, 0, stream>>>(edges, qb, kb, WcatT, bcat, out_H, Pb, psum);
    k_pv   <<<512, 512, 0, stream>>>(Pb, psum, vTb, out_attn);
}